// Round 7
// baseline (190.304 us; speedup 1.0000x reference)
//
#include <hip/hip_runtime.h>
#include <math.h>

#define N_TOK 4098
#define NK_TOK 4099
#define C_DIM 384
#define NKPAD 4160
// HEADS = 6, HD = 64

typedef short  bh8 __attribute__((ext_vector_type(8)));   // 8 bf16 (4 VGPRs)
typedef float  f32x4 __attribute__((ext_vector_type(4)));
typedef unsigned short ushort;
typedef ushort u4 __attribute__((ext_vector_type(4)));
typedef ushort u8 __attribute__((ext_vector_type(8)));

static __device__ __forceinline__ ushort f2bf(float f) {
  unsigned int u = __float_as_uint(f);
  u = (u + 0x7FFF + ((u >> 16) & 1)) >> 16;   // RNE
  return (ushort)u;
}
static __device__ __forceinline__ float bf2f(ushort s) {
  return __uint_as_float(((unsigned int)s) << 16);
}

// ---------------------------------------------------------------------------
// prep: one kernel, independent block roles.
//  b 0..15    : pool partials (256 interior rows each)  [16 partials]
//  b 16       : keep-compaction prefix scan -> inv[], nk
//  b 17..145  : bf16 A-build (32 rows each): Ak = x+pos, Av = x (rows 0..4097)
//  b 146..177 : W fp32->bf16 convert (4 matrices x 8 blocks)
__global__ __launch_bounds__(256) void prep_kernel(
    const float* __restrict__ x, const float* __restrict__ pos,
    const float* __restrict__ mask, const float* __restrict__ mask_block,
    const float* __restrict__ Wq, const float* __restrict__ Wk,
    const float* __restrict__ Wv, const float* __restrict__ Wp,
    float* __restrict__ pooled_part, float* __restrict__ cnt_part,
    int* __restrict__ nk, int* __restrict__ inv,
    ushort* __restrict__ Ak, ushort* __restrict__ Av, ushort* __restrict__ Wb) {
  const int b = blockIdx.x, t = threadIdx.x;
  if (b < 16) {                              // pool partials (256 rows each)
    const int r0 = b * 256;
    float a0 = 0.f, a1 = 0.f;
    int lc = 0;
#pragma unroll 4
    for (int r = r0; r < r0 + 256; ++r) {
      if (mask[r] < 0.5f) {
        a0 += x[(size_t)(r + 1) * C_DIM + t];
        if (t < 128) a1 += x[(size_t)(r + 1) * C_DIM + 256 + t];
        ++lc;
      }
    }
    pooled_part[b * C_DIM + t] = a0;
    if (t < 128) pooled_part[b * C_DIM + 256 + t] = a1;
    if (t == 0) cnt_part[b] = (float)lc;
  } else if (b == 16) {                      // keep-compaction prefix scan
    __shared__ int scnt[256];
    const int j0 = t * 17;
    unsigned int bits = 0;
    int c = 0;
#pragma unroll 1
    for (int u = 0; u < 17; ++u) {
      const int j = j0 + u;
      bool keep = false;
      if (j < NK_TOK)
        keep = (j >= 1 && j <= N_TOK - 2) ? (mask[j - 1] >= 0.5f)
                                          : (mask_block[j] >= 0.5f);
      if (keep) { bits |= 1u << u; ++c; }
    }
    scnt[t] = c;
    __syncthreads();
    for (int d = 1; d < 256; d <<= 1) {
      const int v = scnt[t];
      const int add = (t >= d) ? scnt[t - d] : 0;
      __syncthreads();
      scnt[t] = v + add;
      __syncthreads();
    }
    int base = scnt[t] - c;                  // exclusive prefix
    if (t == 255) *nk = scnt[255];
#pragma unroll 1
    for (int u = 0; u < 17; ++u) {
      const int j = j0 + u;
      if (j < NK_TOK) inv[j] = ((bits >> u) & 1) ? base++ : -1;
    }
  } else if (b < 146) {                      // A-build rows 0..4097
    const int r0 = (b - 17) * 32;
#pragma unroll 3
    for (int i = 0; i < 12; ++i) {
      const int idx = i * 1024 + t * 4;
      const int row = r0 + idx / C_DIM, col = idx % C_DIM;
      if (row >= N_TOK) continue;
      const float4 pv = *(const float4*)&pos[(size_t)row * C_DIM + col];
      const float4 xv = *(const float4*)&x[(size_t)row * C_DIM + col];
      u4 k4 = {f2bf(xv.x + pv.x), f2bf(xv.y + pv.y),
               f2bf(xv.z + pv.z), f2bf(xv.w + pv.w)};
      *(u4*)&Ak[(size_t)row * C_DIM + col] = k4;
      u4 v4 = {f2bf(xv.x), f2bf(xv.y), f2bf(xv.z), f2bf(xv.w)};
      *(u4*)&Av[(size_t)row * C_DIM + col] = v4;
    }
  } else {                                   // W convert
    const int wi = b - 146;                  // 0..31
    const float* src = (wi < 8) ? Wq : (wi < 16) ? Wk : (wi < 24) ? Wv : Wp;
    const int base = (wi >> 3) * 147456 + (wi & 7) * 18432;
#pragma unroll 2
    for (int i = 0; i < 18; ++i) {
      const float4 v = *(const float4*)&src[(wi & 7) * 18432 + i * 1024 + t * 4];
      u4 o = {f2bf(v.x), f2bf(v.y), f2bf(v.z), f2bf(v.w)};
      *(u4*)&Wb[base + i * 1024 + t * 4] = o;
    }
  }
}

// ---------------------------------------------------------------------------
// bf16 MFMA GEMM core: 64x64 out tile, K=384, BK=64, synchronous u8 staging
// with VGPR prefetch of the next K-chunk during compute. Padded LDS [64][72].
static __device__ __forceinline__ void gemm_core(
    const ushort* __restrict__ A, const ushort* __restrict__ B,
    ushort (* __restrict__ As)[72], ushort (* __restrict__ Bs)[72],
    int t, int w, int quad, int l15, f32x4 acc[4]) {
  const int g = t & 7;
  u8 ra[2], rb[2];
#pragma unroll
  for (int it = 0; it < 2; ++it) {
    const int r = it * 32 + (t >> 3);
    ra[it] = *(const u8*)&A[r * C_DIM + g * 8];
    rb[it] = *(const u8*)&B[r * C_DIM + g * 8];
  }
#pragma unroll 1
  for (int kt = 0; kt < 6; ++kt) {
    __syncthreads();
#pragma unroll
    for (int it = 0; it < 2; ++it) {
      const int r = it * 32 + (t >> 3);
      *(u8*)&As[r][g * 8] = ra[it];
      *(u8*)&Bs[r][g * 8] = rb[it];
    }
    __syncthreads();
    if (kt < 5) {
      const int k0 = (kt + 1) * 64;
#pragma unroll
      for (int it = 0; it < 2; ++it) {
        const int r = it * 32 + (t >> 3);
        ra[it] = *(const u8*)&A[r * C_DIM + k0 + g * 8];
        rb[it] = *(const u8*)&B[r * C_DIM + k0 + g * 8];
      }
    }
    const bh8 b0 = *(const bh8*)&Bs[w * 16 + l15][quad * 8];
    const bh8 b1 = *(const bh8*)&Bs[w * 16 + l15][32 + quad * 8];
#pragma unroll
    for (int mb = 0; mb < 4; ++mb) {
      const bh8 a0 = *(const bh8*)&As[mb * 16 + l15][quad * 8];
      const bh8 a1 = *(const bh8*)&As[mb * 16 + l15][32 + quad * 8];
      acc[mb] = __builtin_amdgcn_mfma_f32_16x16x32_bf16(a0, b0, acc[mb], 0, 0, 0);
      acc[mb] = __builtin_amdgcn_mfma_f32_16x16x32_bf16(a1, b1, acc[mb], 0, 0, 0);
    }
  }
}

// ---------------------------------------------------------------------------
// fused Q/K/V projection. grid (66, 18). x<65: y = which*6 + h, normal tiles
// (Q reads Ak, scale 0.125 in epilogue; K/V scatter via inv[], skip m=4098).
// x==65,y==0: back-token matvec block (16-partial pool reduce + Wk/Wv matvec
// -> Kc/Vt at slot inv[4098]).
__global__ __launch_bounds__(256) void gemm3_kernel(
    const ushort* __restrict__ Ak, const ushort* __restrict__ Av,
    const ushort* __restrict__ Wb, const int* __restrict__ inv,
    const float* __restrict__ pooled_part, const float* __restrict__ cnt_part,
    const float* __restrict__ pos, ushort* __restrict__ Qh,
    ushort* __restrict__ Kc, ushort* __restrict__ Vt) {
  __shared__ ushort As[64][72], Bs[64][72];
  __shared__ float skin[C_DIM], svin[C_DIM];
  const int t = threadIdx.x, w = t >> 6, lane = t & 63;
  const int quad = lane >> 4, l15 = lane & 15;
  const int which = blockIdx.y / 6, h = blockIdx.y % 6;

  if (blockIdx.x == 65) {                    // back-token block
    if (blockIdx.y != 0) return;
    float cs = 0.f;
#pragma unroll
    for (int i = 0; i < 16; ++i) cs += cnt_part[i];
    const float ic = 1.f / (cs + 1e-10f);
    for (int c = t; c < C_DIM; c += 256) {
      float s = 0.f;
#pragma unroll
      for (int p = 0; p < 16; ++p) s += pooled_part[p * C_DIM + c];
      const float back = s * ic;
      skin[c] = bf2f(f2bf(back + pos[(size_t)(NK_TOK - 1) * C_DIM + c]));
      svin[c] = bf2f(f2bf(back));
    }
    __syncthreads();
    const int slot = inv[NK_TOK - 1];
    for (int o = t; o < C_DIM; o += 256) {
      const ushort* wk = Wb + 147456 + (size_t)o * C_DIM;
      const ushort* wv = Wb + 294912 + (size_t)o * C_DIM;
      float ka = 0.f, va = 0.f;
#pragma unroll 4
      for (int c8 = 0; c8 < 48; ++c8) {
        const u8 k8 = *(const u8*)&wk[c8 * 8];
        const u8 v8 = *(const u8*)&wv[c8 * 8];
#pragma unroll
        for (int j = 0; j < 8; ++j) {
          ka += bf2f(k8[j]) * skin[c8 * 8 + j];
          va += bf2f(v8[j]) * svin[c8 * 8 + j];
        }
      }
      const int hh = o >> 6, d = o & 63;
      Kc[((size_t)hh * NKPAD + slot) * 64 + d] = f2bf(ka);
      Vt[((size_t)(hh * 64 + d)) * NKPAD + slot] = f2bf(va);
    }
    return;
  }

  const int m0 = blockIdx.x * 64;
  const ushort* A = (which == 2 ? Av : Ak) + (size_t)m0 * C_DIM;
  const ushort* B = Wb + (size_t)which * 147456 + (size_t)h * 64 * C_DIM;
  f32x4 acc[4];
#pragma unroll
  for (int i = 0; i < 4; ++i) acc[i] = (f32x4){0.f, 0.f, 0.f, 0.f};
  gemm_core(A, B, As, Bs, t, w, quad, l15, acc);
  const int n = w * 16 + l15;
  if (which == 0) {
#pragma unroll
    for (int mb = 0; mb < 4; ++mb)
#pragma unroll
      for (int r = 0; r < 4; ++r) {
        const int m = m0 + mb * 16 + quad * 4 + r;
        if (m < N_TOK)
          Qh[((size_t)h * N_TOK + m) * 64 + n] = f2bf(acc[mb][r] * 0.125f);
      }
  } else if (which == 1) {
#pragma unroll
    for (int mb = 0; mb < 4; ++mb)
#pragma unroll
      for (int r = 0; r < 4; ++r) {
        const int m = m0 + mb * 16 + quad * 4 + r;
        if (m < NK_TOK - 1) {                // back row handled by back-block
          const int slot = inv[m];
          if (slot >= 0) Kc[((size_t)h * NKPAD + slot) * 64 + n] = f2bf(acc[mb][r]);
        }
      }
  } else {
#pragma unroll
    for (int mb = 0; mb < 4; ++mb)
#pragma unroll
      for (int r = 0; r < 4; ++r) {
        const int m = m0 + mb * 16 + quad * 4 + r;
        if (m < NK_TOK - 1) {
          const int slot = inv[m];
          if (slot >= 0) Vt[((size_t)(h * 64 + n)) * NKPAD + slot] = f2bf(acc[mb][r]);
        }
      }
  }
}

// ---------------------------------------------------------------------------
// MFMA flash attention (r5-measured structure): 16 q/wave, S^T = K.Q^T per
// wave, padded LDS (27.6 KB -> 5 blocks/CU), synchronous u8 staging with
// VGPR prefetch of the next chunk. grid (65, 6, 3). No fences.
__global__ __launch_bounds__(256) void attn_kernel(
    const ushort* __restrict__ Qh, const ushort* __restrict__ Kc,
    const ushort* __restrict__ Vt, const int* __restrict__ nkp,
    ushort* __restrict__ Opart, float* __restrict__ Lpart) {
  __shared__ ushort Ks[64][72];   // [slot][d]
  __shared__ ushort Vs[64][72];   // [d][slot]
  __shared__ ushort Ps[4][16][72];
  const int t = threadIdx.x, w = t >> 6, lane = t & 63;
  const int quad = lane >> 4, l15 = lane & 15;
  const int h = blockIdx.y, slice = blockIdx.z;
  const int q0 = blockIdx.x * 64;
  const int nk = *nkp, nchunk = (nk + 63) >> 6;
  const int g = t & 7;

  bh8 qf0, qf1;
  {
    int qr = q0 + w * 16 + l15;
    if (qr > N_TOK - 1) qr = N_TOK - 1;        // clamp (stores guarded)
    const ushort* qp = Qh + ((size_t)h * N_TOK + qr) * 64 + quad * 8;
    qf0 = *(const bh8*)qp;
    qf1 = *(const bh8*)(qp + 32);
  }
  f32x4 oacc[4];
#pragma unroll
  for (int i = 0; i < 4; ++i) oacc[i] = (f32x4){0.f, 0.f, 0.f, 0.f};
  float l_r = 0.f;

  const ushort* kb = Kc + (size_t)h * NKPAD * 64;
  const ushort* vb = Vt + (size_t)h * 64 * NKPAD;

  u8 rk[2], rv[2];
  if (slice < nchunk) {
#pragma unroll
    for (int it = 0; it < 2; ++it) {
      const int r = it * 32 + (t >> 3);
      rk[it] = *(const u8*)&kb[(size_t)(slice * 64 + r) * 64 + g * 8];
      rv[it] = *(const u8*)&vb[(size_t)r * NKPAD + slice * 64 + g * 8];
    }
  }
#pragma unroll 1
  for (int kc = slice; kc < nchunk; kc += 3) {
    __syncthreads();                          // previous chunk's readers done
#pragma unroll
    for (int it = 0; it < 2; ++it) {
      const int r = it * 32 + (t >> 3);
      *(u8*)&Ks[r][g * 8] = rk[it];
      *(u8*)&Vs[r][g * 8] = rv[it];
    }
    __syncthreads();
    if (kc + 3 < nchunk) {                    // prefetch next chunk into VGPRs
#pragma unroll
      for (int it = 0; it < 2; ++it) {
        const int r = it * 32 + (t >> 3);
        rk[it] = *(const u8*)&kb[(size_t)((kc + 3) * 64 + r) * 64 + g * 8];
        rv[it] = *(const u8*)&vb[(size_t)r * NKPAD + (kc + 3) * 64 + g * 8];
      }
    }
    float csum = 0.f;
#pragma unroll
    for (int f = 0; f < 4; ++f) {
      f32x4 s4 = {0.f, 0.f, 0.f, 0.f};
      const bh8 a0 = *(const bh8*)&Ks[f * 16 + l15][quad * 8];
      const bh8 a1 = *(const bh8*)&Ks[f * 16 + l15][32 + quad * 8];
      s4 = __builtin_amdgcn_mfma_f32_16x16x32_bf16(a0, qf0, s4, 0, 0, 0);
      s4 = __builtin_amdgcn_mfma_f32_16x16x32_bf16(a1, qf1, s4, 0, 0, 0);
      const int keyb = kc * 64 + f * 16 + quad * 4;
      u4 pv;
#pragma unroll
      for (int r = 0; r < 4; ++r) {
        const float p = (keyb + r < nk) ? __expf(s4[r]) : 0.f;
        csum += p;
        pv[r] = f2bf(p);
      }
      *(u4*)&Ps[w][l15][f * 16 + quad * 4] = pv;
    }
    csum += __shfl_xor(csum, 16);
    csum += __shfl_xor(csum, 32);
    l_r += csum;

    const bh8 pa0 = *(const bh8*)&Ps[w][l15][quad * 8];
    const bh8 pa1 = *(const bh8*)&Ps[w][l15][32 + quad * 8];
#pragma unroll
    for (int db = 0; db < 4; ++db) {
      const bh8 b0 = *(const bh8*)&Vs[db * 16 + l15][quad * 8];
      const bh8 b1 = *(const bh8*)&Vs[db * 16 + l15][32 + quad * 8];
      oacc[db] = __builtin_amdgcn_mfma_f32_16x16x32_bf16(pa0, b0, oacc[db], 0, 0, 0);
      oacc[db] = __builtin_amdgcn_mfma_f32_16x16x32_bf16(pa1, b1, oacc[db], 0, 0, 0);
    }
  }

  const int sh = slice * 6 + h;
  const int qg = q0 + w * 16;
#pragma unroll
  for (int db = 0; db < 4; ++db)
#pragma unroll
    for (int r = 0; r < 4; ++r) {
      const int q = qg + quad * 4 + r;
      if (q < N_TOK)
        Opart[((size_t)sh * NKPAD + q) * 64 + db * 16 + l15] = f2bf(oacc[db][r]);
    }
  if (quad == 0) {
    const int q = qg + l15;
    if (q < N_TOK) Lpart[sh * NKPAD + q] = l_r;
  }
}

// ---------------------------------------------------------------------------
// output projection with fused 3-slice merge in the A-staging (chunk kt of A
// == head kt of the attention output). fp32 out + bias.
__global__ __launch_bounds__(256) void gemm_out_kernel(
    const ushort* __restrict__ Opart, const float* __restrict__ Lpart,
    const ushort* __restrict__ Wpb, const float* __restrict__ bp,
    float* __restrict__ out) {
  __shared__ ushort As[64][72], Bs[64][72];
  const int t = threadIdx.x, w = t >> 6, lane = t & 63;
  const int quad = lane >> 4, l15 = lane & 15;
  const int m0 = blockIdx.x * 64;
  const int n0 = blockIdx.y * 64;
  const int g8 = t & 7;
  f32x4 acc[4];
#pragma unroll
  for (int i = 0; i < 4; ++i) acc[i] = (f32x4){0.f, 0.f, 0.f, 0.f};

  u8 ra[2], rb[2];
#pragma unroll
  for (int it = 0; it < 2; ++it) {
    const int r = it * 32 + (t >> 3), m = m0 + r;
    float l = 0.f;
#pragma unroll
    for (int s = 0; s < 3; ++s) l += Lpart[(s * 6 + 0) * NKPAD + m];
    const float invl = 1.f / l;
    float o[8] = {0, 0, 0, 0, 0, 0, 0, 0};
#pragma unroll
    for (int s = 0; s < 3; ++s) {
      const u8 v = *(const u8*)&Opart[((size_t)(s * 6 + 0) * NKPAD + m) * 64 + g8 * 8];
#pragma unroll
      for (int j = 0; j < 8; ++j) o[j] += bf2f(v[j]);
    }
#pragma unroll
    for (int j = 0; j < 8; ++j) ra[it][j] = f2bf(o[j] * invl);
    rb[it] = *(const u8*)&Wpb[(size_t)(n0 + r) * C_DIM + g8 * 8];
  }
#pragma unroll 1
  for (int kt = 0; kt < 6; ++kt) {
    __syncthreads();
#pragma unroll
    for (int it = 0; it < 2; ++it) {
      const int r = it * 32 + (t >> 3);
      *(u8*)&As[r][g8 * 8] = ra[it];
      *(u8*)&Bs[r][g8 * 8] = rb[it];
    }
    __syncthreads();
    if (kt < 5) {
      const int kh = kt + 1;
#pragma unroll
      for (int it = 0; it < 2; ++it) {
        const int r = it * 32 + (t >> 3), m = m0 + r;
        float l = 0.f;
#pragma unroll
        for (int s = 0; s < 3; ++s) l += Lpart[(s * 6 + kh) * NKPAD + m];
        const float invl = 1.f / l;
        float o[8] = {0, 0, 0, 0, 0, 0, 0, 0};
#pragma unroll
        for (int s = 0; s < 3; ++s) {
          const u8 v = *(const u8*)&Opart[((size_t)(s * 6 + kh) * NKPAD + m) * 64 + g8 * 8];
#pragma unroll
          for (int j = 0; j < 8; ++j) o[j] += bf2f(v[j]);
        }
#pragma unroll
        for (int j = 0; j < 8; ++j) ra[it][j] = f2bf(o[j] * invl);
        rb[it] = *(const u8*)&Wpb[(size_t)(n0 + r) * C_DIM + kh * 64 + g8 * 8];
      }
    }
    const bh8 b0 = *(const bh8*)&Bs[w * 16 + l15][quad * 8];
    const bh8 b1 = *(const bh8*)&Bs[w * 16 + l15][32 + quad * 8];
#pragma unroll
    for (int mb = 0; mb < 4; ++mb) {
      const bh8 a0 = *(const bh8*)&As[mb * 16 + l15][quad * 8];
      const bh8 a1 = *(const bh8*)&As[mb * 16 + l15][32 + quad * 8];
      acc[mb] = __builtin_amdgcn_mfma_f32_16x16x32_bf16(a0, b0, acc[mb], 0, 0, 0);
      acc[mb] = __builtin_amdgcn_mfma_f32_16x16x32_bf16(a1, b1, acc[mb], 0, 0, 0);
    }
  }
  const int n = w * 16 + l15;
  const float bb = bp[n0 + n];
#pragma unroll
  for (int mb = 0; mb < 4; ++mb)
#pragma unroll
    for (int r = 0; r < 4; ++r) {
      const int m = m0 + mb * 16 + quad * 4 + r;
      if (m < N_TOK) out[(size_t)m * C_DIM + n0 + n] = acc[mb][r] + bb;
    }
}

// ---------------------------------------------------------------------------
extern "C" void kernel_launch(void* const* d_in, const int* in_sizes, int n_in,
                              void* d_out, int out_size, void* d_ws, size_t ws_size,
                              hipStream_t stream) {
  const float* x          = (const float*)d_in[0];
  const float* pos        = (const float*)d_in[1];
  const float* mask       = (const float*)d_in[2];
  const float* mask_block = (const float*)d_in[3];
  const float* Wq         = (const float*)d_in[4];
  const float* Wk         = (const float*)d_in[5];
  const float* Wv         = (const float*)d_in[6];
  const float* Wp         = (const float*)d_in[7];
  const float* bp         = (const float*)d_in[8];
  float* out = (float*)d_out;
  char* wsb = (char*)d_ws;

  float*  cnt_part    = (float*)wsb;                // [16]
  int*    nk          = (int*)(wsb + 512);
  int*    inv         = (int*)(wsb + 1024);         // [4099]
  float*  pooled_part = (float*)(wsb + 20480);      // [16][384]
  ushort* Ak          = (ushort*)(wsb + 217088);    // [4160][384]
  ushort* Av          = (ushort*)(wsb + 3411968);   // [4160][384]
  ushort* Wb          = (ushort*)(wsb + 6606848);   // [4][384][384]
  ushort* Qh          = (ushort*)(wsb + 7786496);   // [6][4098][64]
  ushort* Kc          = (ushort*)(wsb + 10933760);  // [6][4160][64]
  ushort* Vt          = (ushort*)(wsb + 14128640);  // [6][64][4160]
  ushort* Op          = (ushort*)(wsb + 17323520);  // [18][4160][64]
  float*  Lp          = (float*)(wsb + 26908160);   // [18][4160]

  prep_kernel<<<dim3(178), dim3(256), 0, stream>>>(
      x, pos, mask, mask_block, Wq, Wk, Wv, Wp,
      pooled_part, cnt_part, nk, inv, Ak, Av, Wb);
  gemm3_kernel<<<dim3(66, 18), dim3(256), 0, stream>>>(
      Ak, Av, Wb, inv, pooled_part, cnt_part, pos, Qh, Kc, Vt);
  attn_kernel<<<dim3(65, 6, 3), dim3(256), 0, stream>>>(Qh, Kc, Vt, nk, Op, Lp);
  gemm_out_kernel<<<dim3(65, 6), dim3(256), 0, stream>>>(Op, Lp, Wb + 3 * 147456,
                                                         bp, out);
}

// Round 8
// 166.495 us; speedup vs baseline: 1.1430x; 1.1430x over previous
//
#include <hip/hip_runtime.h>
#include <math.h>

#define N_TOK 4098
#define NK_TOK 4099
#define C_DIM 384
#define NKPAD 4160
// HEADS = 6, HD = 64

typedef short  bh8 __attribute__((ext_vector_type(8)));   // 8 bf16 (4 VGPRs)
typedef float  f32x4 __attribute__((ext_vector_type(4)));
typedef unsigned short ushort;
typedef ushort u4 __attribute__((ext_vector_type(4)));
typedef ushort u8 __attribute__((ext_vector_type(8)));

static __device__ __forceinline__ ushort f2bf(float f) {
  unsigned int u = __float_as_uint(f);
  u = (u + 0x7FFF + ((u >> 16) & 1)) >> 16;   // RNE
  return (ushort)u;
}
static __device__ __forceinline__ float bf2f(ushort s) {
  return __uint_as_float(((unsigned int)s) << 16);
}

// ---------------------------------------------------------------------------
// prep: one kernel, independent block roles.
//  b 0..63    : pool partials (64 interior rows each, mask staged in LDS)
//  b 64       : keep-compaction prefix scan -> inv[], nk
//  b 65..193  : bf16 A-build (32 rows each): Ak = x+pos, Av = x (rows 0..4097)
//  b 194..225 : W fp32->bf16 convert (4 matrices x 8 blocks)
__global__ __launch_bounds__(256) void prep_kernel(
    const float* __restrict__ x, const float* __restrict__ pos,
    const float* __restrict__ mask, const float* __restrict__ mask_block,
    const float* __restrict__ Wq, const float* __restrict__ Wk,
    const float* __restrict__ Wv, const float* __restrict__ Wp,
    float* __restrict__ pooled_part, float* __restrict__ cnt_part,
    int* __restrict__ nk, int* __restrict__ inv,
    ushort* __restrict__ Ak, ushort* __restrict__ Av, ushort* __restrict__ Wb) {
  const int b = blockIdx.x, t = threadIdx.x;
  if (b < 64) {                              // pool partials (64 rows each)
    __shared__ float smask[64];
    const int r0 = b * 64;
    if (t < 64) smask[t] = mask[r0 + t];
    __syncthreads();
    float a0 = 0.f, a1 = 0.f;
    int lc = 0;
#pragma unroll 8
    for (int i = 0; i < 64; ++i) {
      if (smask[i] < 0.5f) {                 // block-uniform branch, LDS-gated
        a0 += x[(size_t)(r0 + i + 1) * C_DIM + t];
        if (t < 128) a1 += x[(size_t)(r0 + i + 1) * C_DIM + 256 + t];
        ++lc;
      }
    }
    pooled_part[b * C_DIM + t] = a0;
    if (t < 128) pooled_part[b * C_DIM + 256 + t] = a1;
    if (t == 0) cnt_part[b] = (float)lc;
  } else if (b == 64) {                      // keep-compaction prefix scan
    __shared__ int scnt[256];
    const int j0 = t * 17;
    unsigned int bits = 0;
    int c = 0;
#pragma unroll 1
    for (int u = 0; u < 17; ++u) {
      const int j = j0 + u;
      bool keep = false;
      if (j < NK_TOK)
        keep = (j >= 1 && j <= N_TOK - 2) ? (mask[j - 1] >= 0.5f)
                                          : (mask_block[j] >= 0.5f);
      if (keep) { bits |= 1u << u; ++c; }
    }
    scnt[t] = c;
    __syncthreads();
    for (int d = 1; d < 256; d <<= 1) {
      const int v = scnt[t];
      const int add = (t >= d) ? scnt[t - d] : 0;
      __syncthreads();
      scnt[t] = v + add;
      __syncthreads();
    }
    int base = scnt[t] - c;                  // exclusive prefix
    if (t == 255) *nk = scnt[255];
#pragma unroll 1
    for (int u = 0; u < 17; ++u) {
      const int j = j0 + u;
      if (j < NK_TOK) inv[j] = ((bits >> u) & 1) ? base++ : -1;
    }
  } else if (b < 194) {                      // A-build rows 0..4097
    const int r0 = (b - 65) * 32;
#pragma unroll 3
    for (int i = 0; i < 12; ++i) {
      const int idx = i * 1024 + t * 4;
      const int row = r0 + idx / C_DIM, col = idx % C_DIM;
      if (row >= N_TOK) continue;
      const float4 pv = *(const float4*)&pos[(size_t)row * C_DIM + col];
      const float4 xv = *(const float4*)&x[(size_t)row * C_DIM + col];
      u4 k4 = {f2bf(xv.x + pv.x), f2bf(xv.y + pv.y),
               f2bf(xv.z + pv.z), f2bf(xv.w + pv.w)};
      *(u4*)&Ak[(size_t)row * C_DIM + col] = k4;
      u4 v4 = {f2bf(xv.x), f2bf(xv.y), f2bf(xv.z), f2bf(xv.w)};
      *(u4*)&Av[(size_t)row * C_DIM + col] = v4;
    }
  } else {                                   // W convert
    const int wi = b - 194;                  // 0..31
    const float* src = (wi < 8) ? Wq : (wi < 16) ? Wk : (wi < 24) ? Wv : Wp;
    const int base = (wi >> 3) * 147456 + (wi & 7) * 18432;
#pragma unroll 2
    for (int i = 0; i < 18; ++i) {
      const float4 v = *(const float4*)&src[(wi & 7) * 18432 + i * 1024 + t * 4];
      u4 o = {f2bf(v.x), f2bf(v.y), f2bf(v.z), f2bf(v.w)};
      *(u4*)&Wb[base + i * 1024 + t * 4] = o;
    }
  }
}

// ---------------------------------------------------------------------------
// bf16 MFMA GEMM core: 64x64 out tile, K=384, BK=64, synchronous u8 staging
// with VGPR prefetch of the next K-chunk during compute. Padded LDS [64][72].
static __device__ __forceinline__ void gemm_core(
    const ushort* __restrict__ A, const ushort* __restrict__ B,
    ushort (* __restrict__ As)[72], ushort (* __restrict__ Bs)[72],
    int t, int w, int quad, int l15, f32x4 acc[4]) {
  const int g = t & 7;
  u8 ra[2], rb[2];
#pragma unroll
  for (int it = 0; it < 2; ++it) {
    const int r = it * 32 + (t >> 3);
    ra[it] = *(const u8*)&A[r * C_DIM + g * 8];
    rb[it] = *(const u8*)&B[r * C_DIM + g * 8];
  }
#pragma unroll 1
  for (int kt = 0; kt < 6; ++kt) {
    __syncthreads();
#pragma unroll
    for (int it = 0; it < 2; ++it) {
      const int r = it * 32 + (t >> 3);
      *(u8*)&As[r][g * 8] = ra[it];
      *(u8*)&Bs[r][g * 8] = rb[it];
    }
    __syncthreads();
    if (kt < 5) {
      const int k0 = (kt + 1) * 64;
#pragma unroll
      for (int it = 0; it < 2; ++it) {
        const int r = it * 32 + (t >> 3);
        ra[it] = *(const u8*)&A[r * C_DIM + k0 + g * 8];
        rb[it] = *(const u8*)&B[r * C_DIM + k0 + g * 8];
      }
    }
    const bh8 b0 = *(const bh8*)&Bs[w * 16 + l15][quad * 8];
    const bh8 b1 = *(const bh8*)&Bs[w * 16 + l15][32 + quad * 8];
#pragma unroll
    for (int mb = 0; mb < 4; ++mb) {
      const bh8 a0 = *(const bh8*)&As[mb * 16 + l15][quad * 8];
      const bh8 a1 = *(const bh8*)&As[mb * 16 + l15][32 + quad * 8];
      acc[mb] = __builtin_amdgcn_mfma_f32_16x16x32_bf16(a0, b0, acc[mb], 0, 0, 0);
      acc[mb] = __builtin_amdgcn_mfma_f32_16x16x32_bf16(a1, b1, acc[mb], 0, 0, 0);
    }
  }
}

// ---------------------------------------------------------------------------
// fused Q/K/V projection. grid (66, 18). x<65: y = which*6 + h, normal tiles
// (Q reads Ak, scale 0.125 in epilogue; K/V scatter via inv[], skip m=4098).
// x==65,y==0: back-token matvec block (64-partial pool reduce + Wk/Wv matvec
// -> Kc/Vt at slot inv[4098]).
__global__ __launch_bounds__(256) void gemm3_kernel(
    const ushort* __restrict__ Ak, const ushort* __restrict__ Av,
    const ushort* __restrict__ Wb, const int* __restrict__ inv,
    const float* __restrict__ pooled_part, const float* __restrict__ cnt_part,
    const float* __restrict__ pos, ushort* __restrict__ Qh,
    ushort* __restrict__ Kc, ushort* __restrict__ Vt) {
  __shared__ ushort As[64][72], Bs[64][72];
  __shared__ float skin[C_DIM], svin[C_DIM];
  const int t = threadIdx.x, w = t >> 6, lane = t & 63;
  const int quad = lane >> 4, l15 = lane & 15;
  const int which = blockIdx.y / 6, h = blockIdx.y % 6;

  if (blockIdx.x == 65) {                    // back-token block
    if (blockIdx.y != 0) return;
    float cs = 0.f;
#pragma unroll 8
    for (int i = 0; i < 64; ++i) cs += cnt_part[i];
    const float ic = 1.f / (cs + 1e-10f);
    for (int c = t; c < C_DIM; c += 256) {
      float s = 0.f;
#pragma unroll 8
      for (int p = 0; p < 64; ++p) s += pooled_part[p * C_DIM + c];
      const float back = s * ic;
      skin[c] = bf2f(f2bf(back + pos[(size_t)(NK_TOK - 1) * C_DIM + c]));
      svin[c] = bf2f(f2bf(back));
    }
    __syncthreads();
    const int slot = inv[NK_TOK - 1];
    for (int o = t; o < C_DIM; o += 256) {
      const ushort* wk = Wb + 147456 + (size_t)o * C_DIM;
      const ushort* wv = Wb + 294912 + (size_t)o * C_DIM;
      float ka = 0.f, va = 0.f;
#pragma unroll 4
      for (int c8 = 0; c8 < 48; ++c8) {
        const u8 k8 = *(const u8*)&wk[c8 * 8];
        const u8 v8 = *(const u8*)&wv[c8 * 8];
#pragma unroll
        for (int j = 0; j < 8; ++j) {
          ka += bf2f(k8[j]) * skin[c8 * 8 + j];
          va += bf2f(v8[j]) * svin[c8 * 8 + j];
        }
      }
      const int hh = o >> 6, d = o & 63;
      Kc[((size_t)hh * NKPAD + slot) * 64 + d] = f2bf(ka);
      Vt[((size_t)(hh * 64 + d)) * NKPAD + slot] = f2bf(va);
    }
    return;
  }

  const int m0 = blockIdx.x * 64;
  const ushort* A = (which == 2 ? Av : Ak) + (size_t)m0 * C_DIM;
  const ushort* B = Wb + (size_t)which * 147456 + (size_t)h * 64 * C_DIM;
  f32x4 acc[4];
#pragma unroll
  for (int i = 0; i < 4; ++i) acc[i] = (f32x4){0.f, 0.f, 0.f, 0.f};
  gemm_core(A, B, As, Bs, t, w, quad, l15, acc);
  const int n = w * 16 + l15;
  if (which == 0) {
#pragma unroll
    for (int mb = 0; mb < 4; ++mb)
#pragma unroll
      for (int r = 0; r < 4; ++r) {
        const int m = m0 + mb * 16 + quad * 4 + r;
        if (m < N_TOK)
          Qh[((size_t)h * N_TOK + m) * 64 + n] = f2bf(acc[mb][r] * 0.125f);
      }
  } else if (which == 1) {
#pragma unroll
    for (int mb = 0; mb < 4; ++mb)
#pragma unroll
      for (int r = 0; r < 4; ++r) {
        const int m = m0 + mb * 16 + quad * 4 + r;
        if (m < NK_TOK - 1) {                // back row handled by back-block
          const int slot = inv[m];
          if (slot >= 0) Kc[((size_t)h * NKPAD + slot) * 64 + n] = f2bf(acc[mb][r]);
        }
      }
  } else {
#pragma unroll
    for (int mb = 0; mb < 4; ++mb)
#pragma unroll
      for (int r = 0; r < 4; ++r) {
        const int m = m0 + mb * 16 + quad * 4 + r;
        if (m < NK_TOK - 1) {
          const int slot = inv[m];
          if (slot >= 0) Vt[((size_t)(h * 64 + n)) * NKPAD + slot] = f2bf(acc[mb][r]);
        }
      }
  }
}

// ---------------------------------------------------------------------------
// MFMA flash attention (r5-measured structure): 16 q/wave, S^T = K.Q^T per
// wave, padded LDS (27.6 KB -> 5 blocks/CU), synchronous u8 staging with
// VGPR prefetch of the next chunk. grid (65, 6, 3). No fences.
__global__ __launch_bounds__(256) void attn_kernel(
    const ushort* __restrict__ Qh, const ushort* __restrict__ Kc,
    const ushort* __restrict__ Vt, const int* __restrict__ nkp,
    ushort* __restrict__ Opart, float* __restrict__ Lpart) {
  __shared__ ushort Ks[64][72];   // [slot][d]
  __shared__ ushort Vs[64][72];   // [d][slot]
  __shared__ ushort Ps[4][16][72];
  const int t = threadIdx.x, w = t >> 6, lane = t & 63;
  const int quad = lane >> 4, l15 = lane & 15;
  const int h = blockIdx.y, slice = blockIdx.z;
  const int q0 = blockIdx.x * 64;
  const int nk = *nkp, nchunk = (nk + 63) >> 6;
  const int g = t & 7;

  bh8 qf0, qf1;
  {
    int qr = q0 + w * 16 + l15;
    if (qr > N_TOK - 1) qr = N_TOK - 1;        // clamp (stores guarded)
    const ushort* qp = Qh + ((size_t)h * N_TOK + qr) * 64 + quad * 8;
    qf0 = *(const bh8*)qp;
    qf1 = *(const bh8*)(qp + 32);
  }
  f32x4 oacc[4];
#pragma unroll
  for (int i = 0; i < 4; ++i) oacc[i] = (f32x4){0.f, 0.f, 0.f, 0.f};
  float l_r = 0.f;

  const ushort* kb = Kc + (size_t)h * NKPAD * 64;
  const ushort* vb = Vt + (size_t)h * 64 * NKPAD;

  u8 rk[2], rv[2];
  if (slice < nchunk) {
#pragma unroll
    for (int it = 0; it < 2; ++it) {
      const int r = it * 32 + (t >> 3);
      rk[it] = *(const u8*)&kb[(size_t)(slice * 64 + r) * 64 + g * 8];
      rv[it] = *(const u8*)&vb[(size_t)r * NKPAD + slice * 64 + g * 8];
    }
  }
#pragma unroll 1
  for (int kc = slice; kc < nchunk; kc += 3) {
    __syncthreads();                          // previous chunk's readers done
#pragma unroll
    for (int it = 0; it < 2; ++it) {
      const int r = it * 32 + (t >> 3);
      *(u8*)&Ks[r][g * 8] = rk[it];
      *(u8*)&Vs[r][g * 8] = rv[it];
    }
    __syncthreads();
    if (kc + 3 < nchunk) {                    // prefetch next chunk into VGPRs
#pragma unroll
      for (int it = 0; it < 2; ++it) {
        const int r = it * 32 + (t >> 3);
        rk[it] = *(const u8*)&kb[(size_t)((kc + 3) * 64 + r) * 64 + g * 8];
        rv[it] = *(const u8*)&vb[(size_t)r * NKPAD + (kc + 3) * 64 + g * 8];
      }
    }
    float csum = 0.f;
#pragma unroll
    for (int f = 0; f < 4; ++f) {
      f32x4 s4 = {0.f, 0.f, 0.f, 0.f};
      const bh8 a0 = *(const bh8*)&Ks[f * 16 + l15][quad * 8];
      const bh8 a1 = *(const bh8*)&Ks[f * 16 + l15][32 + quad * 8];
      s4 = __builtin_amdgcn_mfma_f32_16x16x32_bf16(a0, qf0, s4, 0, 0, 0);
      s4 = __builtin_amdgcn_mfma_f32_16x16x32_bf16(a1, qf1, s4, 0, 0, 0);
      const int keyb = kc * 64 + f * 16 + quad * 4;
      u4 pv;
#pragma unroll
      for (int r = 0; r < 4; ++r) {
        const float p = (keyb + r < nk) ? __expf(s4[r]) : 0.f;
        csum += p;
        pv[r] = f2bf(p);
      }
      *(u4*)&Ps[w][l15][f * 16 + quad * 4] = pv;
    }
    csum += __shfl_xor(csum, 16);
    csum += __shfl_xor(csum, 32);
    l_r += csum;

    const bh8 pa0 = *(const bh8*)&Ps[w][l15][quad * 8];
    const bh8 pa1 = *(const bh8*)&Ps[w][l15][32 + quad * 8];
#pragma unroll
    for (int db = 0; db < 4; ++db) {
      const bh8 b0 = *(const bh8*)&Vs[db * 16 + l15][quad * 8];
      const bh8 b1 = *(const bh8*)&Vs[db * 16 + l15][32 + quad * 8];
      oacc[db] = __builtin_amdgcn_mfma_f32_16x16x32_bf16(pa0, b0, oacc[db], 0, 0, 0);
      oacc[db] = __builtin_amdgcn_mfma_f32_16x16x32_bf16(pa1, b1, oacc[db], 0, 0, 0);
    }
  }

  const int sh = slice * 6 + h;
  const int qg = q0 + w * 16;
#pragma unroll
  for (int db = 0; db < 4; ++db)
#pragma unroll
    for (int r = 0; r < 4; ++r) {
      const int q = qg + quad * 4 + r;
      if (q < N_TOK)
        Opart[((size_t)sh * NKPAD + q) * 64 + db * 16 + l15] = f2bf(oacc[db][r]);
    }
  if (quad == 0) {
    const int q = qg + l15;
    if (q < N_TOK) Lpart[sh * NKPAD + q] = l_r;
  }
}

// ---------------------------------------------------------------------------
// output projection with fused 3-slice merge in the A-staging (chunk kt of A
// == head kt of the attention output). fp32 out + bias.
__global__ __launch_bounds__(256) void gemm_out_kernel(
    const ushort* __restrict__ Opart, const float* __restrict__ Lpart,
    const ushort* __restrict__ Wpb, const float* __restrict__ bp,
    float* __restrict__ out) {
  __shared__ ushort As[64][72], Bs[64][72];
  const int t = threadIdx.x, w = t >> 6, lane = t & 63;
  const int quad = lane >> 4, l15 = lane & 15;
  const int m0 = blockIdx.x * 64;
  const int n0 = blockIdx.y * 64;
  const int g8 = t & 7;
  f32x4 acc[4];
#pragma unroll
  for (int i = 0; i < 4; ++i) acc[i] = (f32x4){0.f, 0.f, 0.f, 0.f};

  u8 ra[2], rb[2];
#pragma unroll
  for (int it = 0; it < 2; ++it) {
    const int r = it * 32 + (t >> 3), m = m0 + r;
    float l = 0.f;
#pragma unroll
    for (int s = 0; s < 3; ++s) l += Lpart[(s * 6 + 0) * NKPAD + m];
    const float invl = 1.f / l;
    float o[8] = {0, 0, 0, 0, 0, 0, 0, 0};
#pragma unroll
    for (int s = 0; s < 3; ++s) {
      const u8 v = *(const u8*)&Opart[((size_t)(s * 6 + 0) * NKPAD + m) * 64 + g8 * 8];
#pragma unroll
      for (int j = 0; j < 8; ++j) o[j] += bf2f(v[j]);
    }
#pragma unroll
    for (int j = 0; j < 8; ++j) ra[it][j] = f2bf(o[j] * invl);
    rb[it] = *(const u8*)&Wpb[(size_t)(n0 + r) * C_DIM + g8 * 8];
  }
#pragma unroll 1
  for (int kt = 0; kt < 6; ++kt) {
    __syncthreads();
#pragma unroll
    for (int it = 0; it < 2; ++it) {
      const int r = it * 32 + (t >> 3);
      *(u8*)&As[r][g8 * 8] = ra[it];
      *(u8*)&Bs[r][g8 * 8] = rb[it];
    }
    __syncthreads();
    if (kt < 5) {
      const int kh = kt + 1;
#pragma unroll
      for (int it = 0; it < 2; ++it) {
        const int r = it * 32 + (t >> 3), m = m0 + r;
        float l = 0.f;
#pragma unroll
        for (int s = 0; s < 3; ++s) l += Lpart[(s * 6 + kh) * NKPAD + m];
        const float invl = 1.f / l;
        float o[8] = {0, 0, 0, 0, 0, 0, 0, 0};
#pragma unroll
        for (int s = 0; s < 3; ++s) {
          const u8 v = *(const u8*)&Opart[((size_t)(s * 6 + kh) * NKPAD + m) * 64 + g8 * 8];
#pragma unroll
          for (int j = 0; j < 8; ++j) o[j] += bf2f(v[j]);
        }
#pragma unroll
        for (int j = 0; j < 8; ++j) ra[it][j] = f2bf(o[j] * invl);
        rb[it] = *(const u8*)&Wpb[(size_t)(n0 + r) * C_DIM + kh * 64 + g8 * 8];
      }
    }
    const bh8 b0 = *(const bh8*)&Bs[w * 16 + l15][quad * 8];
    const bh8 b1 = *(const bh8*)&Bs[w * 16 + l15][32 + quad * 8];
#pragma unroll
    for (int mb = 0; mb < 4; ++mb) {
      const bh8 a0 = *(const bh8*)&As[mb * 16 + l15][quad * 8];
      const bh8 a1 = *(const bh8*)&As[mb * 16 + l15][32 + quad * 8];
      acc[mb] = __builtin_amdgcn_mfma_f32_16x16x32_bf16(a0, b0, acc[mb], 0, 0, 0);
      acc[mb] = __builtin_amdgcn_mfma_f32_16x16x32_bf16(a1, b1, acc[mb], 0, 0, 0);
    }
  }
  const int n = w * 16 + l15;
  const float bb = bp[n0 + n];
#pragma unroll
  for (int mb = 0; mb < 4; ++mb)
#pragma unroll
    for (int r = 0; r < 4; ++r) {
      const int m = m0 + mb * 16 + quad * 4 + r;
      if (m < N_TOK) out[(size_t)m * C_DIM + n0 + n] = acc[mb][r] + bb;
    }
}

// ---------------------------------------------------------------------------
extern "C" void kernel_launch(void* const* d_in, const int* in_sizes, int n_in,
                              void* d_out, int out_size, void* d_ws, size_t ws_size,
                              hipStream_t stream) {
  const float* x          = (const float*)d_in[0];
  const float* pos        = (const float*)d_in[1];
  const float* mask       = (const float*)d_in[2];
  const float* mask_block = (const float*)d_in[3];
  const float* Wq         = (const float*)d_in[4];
  const float* Wk         = (const float*)d_in[5];
  const float* Wv         = (const float*)d_in[6];
  const float* Wp         = (const float*)d_in[7];
  const float* bp         = (const float*)d_in[8];
  float* out = (float*)d_out;
  char* wsb = (char*)d_ws;

  float*  cnt_part    = (float*)wsb;                // [64]
  int*    nk          = (int*)(wsb + 512);
  int*    inv         = (int*)(wsb + 1024);         // [4099]
  float*  pooled_part = (float*)(wsb + 20480);      // [64][384]
  ushort* Ak          = (ushort*)(wsb + 217088);    // [4160][384]
  ushort* Av          = (ushort*)(wsb + 3411968);   // [4160][384]
  ushort* Wb          = (ushort*)(wsb + 6606848);   // [4][384][384]
  ushort* Qh          = (ushort*)(wsb + 7786496);   // [6][4098][64]
  ushort* Kc          = (ushort*)(wsb + 10933760);  // [6][4160][64]
  ushort* Vt          = (ushort*)(wsb + 14128640);  // [6][64][4160]
  ushort* Op          = (ushort*)(wsb + 17323520);  // [18][4160][64]
  float*  Lp          = (float*)(wsb + 26908160);   // [18][4160]

  prep_kernel<<<dim3(226), dim3(256), 0, stream>>>(
      x, pos, mask, mask_block, Wq, Wk, Wv, Wp,
      pooled_part, cnt_part, nk, inv, Ak, Av, Wb);
  gemm3_kernel<<<dim3(66, 18), dim3(256), 0, stream>>>(
      Ak, Av, Wb, inv, pooled_part, cnt_part, pos, Qh, Kc, Vt);
  attn_kernel<<<dim3(65, 6, 3), dim3(256), 0, stream>>>(Qh, Kc, Vt, nk, Op, Lp);
  gemm_out_kernel<<<dim3(65, 6), dim3(256), 0, stream>>>(Op, Lp, Wb + 3 * 147456,
                                                         bp, out);
}